// Round 3
// baseline (1287.813 us; speedup 1.0000x reference)
//
#include <hip/hip_runtime.h>

// ---------------------------------------------------------------------------
// S = D = 4096 single-head attention (with the module's v-transpose bug).
// All six 4096^3 matmuls are NT GEMMs: C[m,n] = sum_k A[m,k]B[n,k].
// Round 3: 256x256 8-wave schedule with one-phase-ahead ds_read prefetch,
// deadline-aligned staging, two counted vmcnt(2) waits per K-tile.
// ---------------------------------------------------------------------------

typedef __attribute__((ext_vector_type(4))) float f32x4;
typedef __attribute__((ext_vector_type(8))) short short8;
typedef __attribute__((ext_vector_type(4))) unsigned short us4;

#define DIM 4096
#define NT  64   // K tiles of 64

__device__ __forceinline__ unsigned short f2bf(float f) {
    unsigned int u = __builtin_bit_cast(unsigned int, f);
    u += 0x7fffu + ((u >> 16) & 1u);   // round-to-nearest-even
    return (unsigned short)(u >> 16);
}

__device__ __forceinline__ void gll16(const void* g, void* l) {
    __builtin_amdgcn_global_load_lds(
        (const __attribute__((address_space(1))) unsigned int*)g,
        (__attribute__((address_space(3))) unsigned int*)l,
        16, 0, 0);
}

// ---------------------------------------------------------------------------
__global__ void cast_kernel(const float* __restrict__ in, unsigned short* __restrict__ out) {
    const size_t i = ((size_t)blockIdx.x * 256 + threadIdx.x) * 4;
    float4 x = *(const float4*)(in + i);
    us4 y;
    y.x = f2bf(x.x); y.y = f2bf(x.y); y.z = f2bf(x.z); y.w = f2bf(x.w);
    *(us4*)(out + i) = y;
}

// ---------------------------------------------------------------------------
// 256x256 NT GEMM, BK=64, 8 waves (2x4), 128 KiB LDS dbuf, st_16x32 swizzle
// via pre-swizzled global source. Phases/tile: Q00,Q01,Q11,Q10.
//   p0: read b1(t);           stage A(t+1)h1; Q00(a_lo,b0)
//   p1: read a_hi(t);         stage B(t+1)p0; Q01(a_lo,b1)
//   p2:                       stage B(t+1)p1; Q11(a_hi,b1); W1 vmcnt(2)
//   p3: read a_lo,b0 (t+1);   stage A(t+2)h0; Q10(a_hi,b0); W2 vmcnt(2)
// EPI: 0 = bf16 out (+opt bias), 1 = f32 out * 1/64, 2 = f32 out + bias + res
// ---------------------------------------------------------------------------
template <int EPI>
__global__ __launch_bounds__(512, 2)
void gemm256(const unsigned short* __restrict__ A, const unsigned short* __restrict__ B,
             void* __restrict__ Cout, const float* __restrict__ bias,
             const float* __restrict__ res) {
    __shared__ alignas(16) char lds[131072];

    const int tid = threadIdx.x;
    const int w = tid >> 6, l = tid & 63;
    const int wr = w >> 2, wc = w & 3;          // 2 x 4 waves, wave tile 128x64

    // bijective XCD swizzle (256 blocks, 8 XCDs)
    const int bid = blockIdx.x;
    const int swz = (bid & 7) * 32 + (bid >> 3);
    const int row0 = (swz >> 4) << 8;
    const int col0 = (swz & 15) << 8;

    // lane constants
    const int laneA  = (l & 15) * 64 + (((l >> 4) << 4) ^ ((l & 8) << 2)); // swizzled frag-read byte
    const int sl_row = l >> 2;                                  // staging row within subtile
    const int sl_col = ((l & 3) << 3) ^ ((l & 32) ? 16 : 0);    // staging col elem (inverse swz)

    f32x4 acc[8][4];
    const f32x4 zero = {0.f, 0.f, 0.f, 0.f};
#pragma unroll
    for (int m = 0; m < 8; ++m)
#pragma unroll
        for (int n = 0; n < 4; ++n) acc[m][n] = zero;

    char* const ldsp = (char*)lds;
    char* const A0 = ldsp;
    char* const B0 = ldsp + 32768;
    char* const A1 = ldsp + 65536;
    char* const B1 = ldsp + 98304;

    const int aoff = wr * 16384 + laneA;
    const int boff = wc * 8192 + laneA;

    // stage A half-tile h (rows h*128..+127) of K-tile t into Abase (16 subtiles)
    auto stageA = [&](const unsigned short* __restrict__ M, char* Abase, int base, int t, int h) {
        const int c1 = w & 1;
        const int r1 = h * 8 + (w >> 1);
        gll16(M + (size_t)(base + r1 * 16 + sl_row) * DIM + t * 64 + c1 * 32 + sl_col,
              Abase + ((r1 * 2 + c1) << 10));
        const int r2 = h * 8 + 4 + (w >> 1);
        gll16(M + (size_t)(base + r2 * 16 + sl_row) * DIM + t * 64 + c1 * 32 + sl_col,
              Abase + ((r2 * 2 + c1) << 10));
    };
    // stage B row-groups: part 0 -> rgs {0,1,4,5,8,9,12,13} (b0 rows),
    //                     part 1 -> +2 (b1 rows)
    auto stageB = [&](const unsigned short* __restrict__ M, char* Bbase, int base, int t, int part) {
        const int c1 = w & 1;
        const int q1 = w >> 1;
        const int r1 = ((q1 >> 1) << 2) + (q1 & 1) + part * 2;
        gll16(M + (size_t)(base + r1 * 16 + sl_row) * DIM + t * 64 + c1 * 32 + sl_col,
              Bbase + ((r1 * 2 + c1) << 10));
        const int q2 = 4 + q1;
        const int r2 = ((q2 >> 1) << 2) + (q2 & 1) + part * 2;
        gll16(M + (size_t)(base + r2 * 16 + sl_row) * DIM + t * 64 + c1 * 32 + sl_col,
              Bbase + ((r2 * 2 + c1) << 10));
    };

    short8 alo[4][2], ahi[4][2], b1r[2][2], b0A[2][2], b0B[2][2];

    // ---- prologue: tile0 (4 units) + A(1)h0 in flight; then prefetch reads ----
    stageA(A, A0, row0, 0, 0);
    stageA(A, A0, row0, 0, 1);
    stageB(B, B0, col0, 0, 0);
    stageB(B, B0, col0, 0, 1);
    stageA(A, A1, row0, 1, 0);
    asm volatile("s_waitcnt vmcnt(2)\ns_barrier" ::: "memory");
#pragma unroll
    for (int m2 = 0; m2 < 4; ++m2)
#pragma unroll
        for (int ks = 0; ks < 2; ++ks)
            alo[m2][ks] = *(const short8*)(A0 + aoff + ((m2 * 2 + ks) << 10));
#pragma unroll
    for (int n2 = 0; n2 < 2; ++n2)
#pragma unroll
        for (int ks = 0; ks < 2; ++ks)
            b0A[n2][ks] = *(const short8*)(B0 + boff + ((n2 * 2 + ks) << 10));

    auto body = [&](int t, const char* Ab, const char* Bb, char* An, char* Bn, char* Ac,
                    short8 (&b0c)[2][2], short8 (&b0n)[2][2]) {
        const int t1 = (t + 1 < NT) ? t + 1 : NT - 1;   // tail re-stages same bytes
        const int t2 = (t + 2 < NT) ? t + 2 : NT - 1;

        // ---------- p0 : read b1(t); stage A(t+1)h1; Q00 ----------
#pragma unroll
        for (int n2 = 0; n2 < 2; ++n2)
#pragma unroll
            for (int ks = 0; ks < 2; ++ks)
                b1r[n2][ks] = *(const short8*)(Bb + boff + (((2 + n2) * 2 + ks) << 10));
        stageA(A, An, row0, t1, 1);
        __builtin_amdgcn_s_barrier();
        __builtin_amdgcn_s_setprio(1);
#pragma unroll
        for (int m2 = 0; m2 < 4; ++m2)
#pragma unroll
            for (int n2 = 0; n2 < 2; ++n2)
#pragma unroll
                for (int ks = 0; ks < 2; ++ks)
                    acc[m2][n2] = __builtin_amdgcn_mfma_f32_16x16x32_bf16(
                        alo[m2][ks], b0c[n2][ks], acc[m2][n2], 0, 0, 0);
        __builtin_amdgcn_s_setprio(0);
        __builtin_amdgcn_s_barrier();

        // ---------- p1 : read a_hi(t); stage B(t+1) b0-rows; Q01 ----------
#pragma unroll
        for (int m2 = 0; m2 < 4; ++m2)
#pragma unroll
            for (int ks = 0; ks < 2; ++ks)
                ahi[m2][ks] = *(const short8*)(Ab + aoff + (((4 + m2) * 2 + ks) << 10));
        stageB(B, Bn, col0, t1, 0);
        __builtin_amdgcn_s_barrier();
        __builtin_amdgcn_s_setprio(1);
#pragma unroll
        for (int m2 = 0; m2 < 4; ++m2)
#pragma unroll
            for (int n2 = 0; n2 < 2; ++n2)
#pragma unroll
                for (int ks = 0; ks < 2; ++ks)
                    acc[m2][2 + n2] = __builtin_amdgcn_mfma_f32_16x16x32_bf16(
                        alo[m2][ks], b1r[n2][ks], acc[m2][2 + n2], 0, 0, 0);
        __builtin_amdgcn_s_setprio(0);
        __builtin_amdgcn_s_barrier();

        // ---------- p2 : stage B(t+1) b1-rows; Q11; W1 ----------
        stageB(B, Bn, col0, t1, 1);
        __builtin_amdgcn_s_barrier();
        __builtin_amdgcn_s_setprio(1);
#pragma unroll
        for (int m2 = 0; m2 < 4; ++m2)
#pragma unroll
            for (int n2 = 0; n2 < 2; ++n2)
#pragma unroll
                for (int ks = 0; ks < 2; ++ks)
                    acc[4 + m2][2 + n2] = __builtin_amdgcn_mfma_f32_16x16x32_bf16(
                        ahi[m2][ks], b1r[n2][ks], acc[4 + m2][2 + n2], 0, 0, 0);
        __builtin_amdgcn_s_setprio(0);
        // W1: A(t+1) + B(t+1) b0-rows landed (issued >=1 phase ago);
        // B(t+1) b1-rows (2 newest) stay in flight.
        asm volatile("s_waitcnt vmcnt(2)\ns_barrier" ::: "memory");

        // ---------- p3 : prefetch a_lo,b0 (t+1); stage A(t+2)h0; Q10; W2 ----------
#pragma unroll
        for (int m2 = 0; m2 < 4; ++m2)
#pragma unroll
            for (int ks = 0; ks < 2; ++ks)
                alo[m2][ks] = *(const short8*)(An + aoff + ((m2 * 2 + ks) << 10));
#pragma unroll
        for (int n2 = 0; n2 < 2; ++n2)
#pragma unroll
            for (int ks = 0; ks < 2; ++ks)
                b0n[n2][ks] = *(const short8*)(Bn + boff + ((n2 * 2 + ks) << 10));
        stageA(A, Ac, row0, t2, 0);
        __builtin_amdgcn_s_barrier();
        __builtin_amdgcn_s_setprio(1);
#pragma unroll
        for (int m2 = 0; m2 < 4; ++m2)
#pragma unroll
            for (int n2 = 0; n2 < 2; ++n2)
#pragma unroll
                for (int ks = 0; ks < 2; ++ks)
                    acc[4 + m2][n2] = __builtin_amdgcn_mfma_f32_16x16x32_bf16(
                        ahi[m2][ks], b0c[n2][ks], acc[4 + m2][n2], 0, 0, 0);
        __builtin_amdgcn_s_setprio(0);
        // W2: B(t+1) b1-rows landed; A(t+2)h0 (2 newest) stays in flight.
        asm volatile("s_waitcnt vmcnt(2)\ns_barrier" ::: "memory");
    };

#pragma unroll 1
    for (int tt = 0; tt < NT / 2; ++tt) {
        body(2 * tt,     A0, B0, A1, B1, A0, b0A, b0B);
        body(2 * tt + 1, A1, B1, A0, B0, A1, b0B, b0A);
    }
    asm volatile("s_waitcnt vmcnt(0)" ::: "memory");

    // ---- epilogue: D col = lane&15, row = (lane>>4)*4 + r ----
#pragma unroll
    for (int mf = 0; mf < 8; ++mf) {
        const int grow0 = row0 + wr * 128 + mf * 16 + ((l >> 4) << 2);
#pragma unroll
        for (int nf = 0; nf < 4; ++nf) {
            const int gcol = col0 + wc * 64 + nf * 16 + (l & 15);
            float bias_v = 0.f;
            if constexpr (EPI != 1) {
                if (bias) bias_v = bias[gcol];
            }
#pragma unroll
            for (int r = 0; r < 4; ++r) {
                const size_t idx = (size_t)(grow0 + r) * DIM + gcol;
                const float x = acc[mf][nf][r] + bias_v;
                if constexpr (EPI == 0) {
                    ((unsigned short*)Cout)[idx] = f2bf(x);
                } else if constexpr (EPI == 1) {
                    ((float*)Cout)[idx] = x * 0.015625f;   // 1/64
                } else {
                    ((float*)Cout)[idx] = x + res[idx];
                }
            }
        }
    }
}

// ---------------------------------------------------------------------------
__global__ __launch_bounds__(256)
void softmax_kernel(const float* __restrict__ S, unsigned short* __restrict__ P) {
    const int row = blockIdx.x;
    const int t = threadIdx.x;
    const float* src = S + (size_t)row * DIM;

    float v[16];
#pragma unroll
    for (int i = 0; i < 16; ++i) v[i] = src[t + (i << 8)];

    float m = v[0];
#pragma unroll
    for (int i = 1; i < 16; ++i) m = fmaxf(m, v[i]);
#pragma unroll
    for (int off = 32; off > 0; off >>= 1) m = fmaxf(m, __shfl_xor(m, off));

    __shared__ float redm[4], reds[4];
    if ((t & 63) == 0) redm[t >> 6] = m;
    __syncthreads();
    m = fmaxf(fmaxf(redm[0], redm[1]), fmaxf(redm[2], redm[3]));

    float s = 0.f;
#pragma unroll
    for (int i = 0; i < 16; ++i) {
        v[i] = expf(v[i] - m);
        s += v[i];
    }
#pragma unroll
    for (int off = 32; off > 0; off >>= 1) s += __shfl_xor(s, off);
    if ((t & 63) == 0) reds[t >> 6] = s;
    __syncthreads();
    s = (reds[0] + reds[1]) + (reds[2] + reds[3]);

    const float inv = 1.0f / s;
    unsigned short* dst = P + (size_t)row * DIM;
#pragma unroll
    for (int i = 0; i < 16; ++i) dst[t + (i << 8)] = f2bf(v[i] * inv);
}

// ---------------------------------------------------------------------------
extern "C" void kernel_launch(void* const* d_in, const int* in_sizes, int n_in,
                              void* d_out, int out_size, void* d_ws, size_t ws_size,
                              hipStream_t stream) {
    const float* query = (const float*)d_in[0];
    const float* key   = (const float*)d_in[1];
    const float* value = (const float*)d_in[2];
    const float* Wq    = (const float*)d_in[3];
    const float* bq    = (const float*)d_in[4];
    const float* Wk    = (const float*)d_in[5];
    const float* bk    = (const float*)d_in[6];
    const float* Wv    = (const float*)d_in[7];
    const float* bv    = (const float*)d_in[8];
    const float* Wo    = (const float*)d_in[9];
    const float* bo    = (const float*)d_in[10];

    const size_t SZ = (size_t)DIM * DIM;
    unsigned short* qb   = (unsigned short*)d_ws;
    unsigned short* kb   = qb + SZ;
    unsigned short* vb   = kb + SZ;
    unsigned short* xb   = vb + SZ;          // reused cast buffer (inputs)
    unsigned short* wb   = xb + SZ;          // reused cast buffer (weights)
    unsigned short* Pb   = wb + SZ;
    unsigned short* ctxb = Pb + SZ;
    float* scores = (float*)(ctxb + SZ);     // 4*SZ bytes

    const dim3 cg(16384), cb(256);
    const dim3 gg(256), gb(512);

    // q = query @ Wq.T + bq
    cast_kernel<<<cg, cb, 0, stream>>>(query, xb);
    cast_kernel<<<cg, cb, 0, stream>>>(Wq, wb);
    gemm256<0><<<gg, gb, 0, stream>>>(xb, wb, qb, bq, nullptr);
    // k = key @ Wk.T + bk
    cast_kernel<<<cg, cb, 0, stream>>>(key, xb);
    cast_kernel<<<cg, cb, 0, stream>>>(Wk, wb);
    gemm256<0><<<gg, gb, 0, stream>>>(xb, wb, kb, bk, nullptr);
    // v = value @ Wv.T + bv
    cast_kernel<<<cg, cb, 0, stream>>>(value, xb);
    cast_kernel<<<cg, cb, 0, stream>>>(Wv, wb);
    gemm256<0><<<gg, gb, 0, stream>>>(xb, wb, vb, bv, nullptr);
    // scores = q @ k.T / 64   (fp32)
    gemm256<1><<<gg, gb, 0, stream>>>(qb, kb, scores, nullptr, nullptr);
    // P = softmax(scores)  (bf16)
    softmax_kernel<<<4096, 256, 0, stream>>>(scores, Pb);
    // ctx = P @ v.T  (the v-transpose bug makes this NT too)
    gemm256<0><<<gg, gb, 0, stream>>>(Pb, vb, ctxb, nullptr, nullptr);
    // out = ctx @ Wo.T + bo + value   (fp32)
    cast_kernel<<<cg, cb, 0, stream>>>(Wo, wb);
    gemm256<2><<<gg, gb, 0, stream>>>(ctxb, wb, d_out, bo, value);
}

// Round 4
// 851.273 us; speedup vs baseline: 1.5128x; 1.5128x over previous
//
#include <hip/hip_runtime.h>

// ---------------------------------------------------------------------------
// S = D = 4096 single-head attention (with the module's v-transpose bug).
// All six 4096^3 matmuls are NT GEMMs: C[m,n] = sum_k A[m,k]B[n,k].
// Round 4: round-2 phase structure (reads+stage / barrier / lgkmcnt(0) /
// MFMA / barrier) with FULL-TILE-AHEAD staging: tile t+2 staged during tile
// t's phases (B at P2, A at P3), one counted vmcnt(8) per K-tile boundary.
// ---------------------------------------------------------------------------

typedef __attribute__((ext_vector_type(4))) float f32x4;
typedef __attribute__((ext_vector_type(8))) short short8;
typedef __attribute__((ext_vector_type(4))) unsigned short us4;

#define DIM 4096
#define NT  64   // K tiles of 64

__device__ __forceinline__ unsigned short f2bf(float f) {
    unsigned int u = __builtin_bit_cast(unsigned int, f);
    u += 0x7fffu + ((u >> 16) & 1u);   // round-to-nearest-even
    return (unsigned short)(u >> 16);
}

__device__ __forceinline__ void gll16(const void* g, void* l) {
    __builtin_amdgcn_global_load_lds(
        (const __attribute__((address_space(1))) unsigned int*)g,
        (__attribute__((address_space(3))) unsigned int*)l,
        16, 0, 0);
}

// ---------------------------------------------------------------------------
__global__ void cast_kernel(const float* __restrict__ in, unsigned short* __restrict__ out) {
    const size_t i = ((size_t)blockIdx.x * 256 + threadIdx.x) * 4;
    float4 x = *(const float4*)(in + i);
    us4 y;
    y.x = f2bf(x.x); y.y = f2bf(x.y); y.z = f2bf(x.z); y.w = f2bf(x.w);
    *(us4*)(out + i) = y;
}

// ---------------------------------------------------------------------------
// 256x256 NT GEMM, BK=64, 8 waves (2x4), 128 KiB LDS dbuf, st_16x32 swizzle
// via pre-swizzled global source.
// Per K-tile t (buffer p = t&1):
//   P0: read a_lo,b0;                       barrier lgkm0 Q00 barrier
//   P1: read b1;                            barrier lgkm0 Q01 barrier
//   P2: read a_hi; stage B(t+2) h0+h1;      barrier lgkm0 Q11 barrier
//   P3: stage A(t+2) h0+h1;                 barrier       Q10 [vmcnt(8)+barrier]
// Tile t+1 was staged one full tile earlier -> ~4 phases of flight before
// its covering vmcnt(8), so the boundary wait retires without stalling.
// EPI: 0 = bf16 out (+opt bias), 1 = f32 out * 1/64, 2 = f32 out + bias + res
// ---------------------------------------------------------------------------
template <int EPI>
__global__ __launch_bounds__(512, 2)
void gemm256(const unsigned short* __restrict__ A, const unsigned short* __restrict__ B,
             void* __restrict__ Cout, const float* __restrict__ bias,
             const float* __restrict__ res) {
    __shared__ alignas(16) char lds[131072];

    const int tid = threadIdx.x;
    const int w = tid >> 6, l = tid & 63;
    const int wr = w >> 2, wc = w & 3;          // 2 x 4 waves, wave tile 128x64

    // bijective XCD swizzle (256 blocks, 8 XCDs)
    const int bid = blockIdx.x;
    const int swz = (bid & 7) * 32 + (bid >> 3);
    const int row0 = (swz >> 4) << 8;
    const int col0 = (swz & 15) << 8;

    // lane constants
    const int laneA  = (l & 15) * 64 + (((l >> 4) << 4) ^ ((l & 8) << 2)); // swizzled frag-read byte
    const int sl_row = l >> 2;                                  // staging row within subtile
    const int sl_col = ((l & 3) << 3) ^ ((l & 32) ? 16 : 0);    // staging col elem (inverse swz)

    f32x4 acc[8][4];
    const f32x4 zero = {0.f, 0.f, 0.f, 0.f};
#pragma unroll
    for (int m = 0; m < 8; ++m)
#pragma unroll
        for (int n = 0; n < 4; ++n) acc[m][n] = zero;

    char* const ldsp = (char*)lds;
    char* const A0 = ldsp;
    char* const B0 = ldsp + 32768;
    char* const A1 = ldsp + 65536;
    char* const B1 = ldsp + 98304;

    const int aoff = wr * 16384 + laneA;
    const int boff = wc * 8192 + laneA;

    // stage half-tile h (row-groups h*8 .. h*8+7) of K-tile t: 2 gll16/thread
    auto stageH = [&](const unsigned short* __restrict__ M, char* ldsbase, int rowbase,
                      int t, int h) {
        const int c1 = w & 1;
        const int r1 = h * 8 + (w >> 1);
        gll16(M + (size_t)(rowbase + r1 * 16 + sl_row) * DIM + t * 64 + c1 * 32 + sl_col,
              ldsbase + ((r1 * 2 + c1) << 10));
        const int r2 = h * 8 + 4 + (w >> 1);
        gll16(M + (size_t)(rowbase + r2 * 16 + sl_row) * DIM + t * 64 + c1 * 32 + sl_col,
              ldsbase + ((r2 * 2 + c1) << 10));
    };

    // ---- prologue: stage tiles 0 and 1 completely; drain tile0 (8 newest fly) ----
    stageH(B, B0, col0, 0, 0); stageH(B, B0, col0, 0, 1);
    stageH(A, A0, row0, 0, 0); stageH(A, A0, row0, 0, 1);
    stageH(B, B1, col0, 1, 0); stageH(B, B1, col0, 1, 1);
    stageH(A, A1, row0, 1, 0); stageH(A, A1, row0, 1, 1);
    asm volatile("s_waitcnt vmcnt(8)\ns_barrier" ::: "memory");

    // one K-tile: 4 phases; stages tile ts (= t+2 clamped) into As/Bs (same parity as t)
    auto body = [&](int t, const char* Ab, const char* Bb, char* As, char* Bs, int ts) {
        short8 alo[4][2], ahi[4][2], b0r[2][2], b1r[2][2];

        // ---------- P0 : read a_lo, b0; Q00 ----------
#pragma unroll
        for (int m2 = 0; m2 < 4; ++m2)
#pragma unroll
            for (int ks = 0; ks < 2; ++ks)
                alo[m2][ks] = *(const short8*)(Ab + aoff + ((m2 * 2 + ks) << 10));
#pragma unroll
        for (int n2 = 0; n2 < 2; ++n2)
#pragma unroll
            for (int ks = 0; ks < 2; ++ks)
                b0r[n2][ks] = *(const short8*)(Bb + boff + ((n2 * 2 + ks) << 10));
        __builtin_amdgcn_s_barrier();
        asm volatile("s_waitcnt lgkmcnt(0)");
        __builtin_amdgcn_s_setprio(1);
#pragma unroll
        for (int m2 = 0; m2 < 4; ++m2)
#pragma unroll
            for (int n2 = 0; n2 < 2; ++n2)
#pragma unroll
                for (int ks = 0; ks < 2; ++ks)
                    acc[m2][n2] = __builtin_amdgcn_mfma_f32_16x16x32_bf16(
                        alo[m2][ks], b0r[n2][ks], acc[m2][n2], 0, 0, 0);
        __builtin_amdgcn_s_setprio(0);
        __builtin_amdgcn_s_barrier();

        // ---------- P1 : read b1; Q01 ----------
#pragma unroll
        for (int n2 = 0; n2 < 2; ++n2)
#pragma unroll
            for (int ks = 0; ks < 2; ++ks)
                b1r[n2][ks] = *(const short8*)(Bb + boff + (((2 + n2) * 2 + ks) << 10));
        __builtin_amdgcn_s_barrier();
        asm volatile("s_waitcnt lgkmcnt(0)");
        __builtin_amdgcn_s_setprio(1);
#pragma unroll
        for (int m2 = 0; m2 < 4; ++m2)
#pragma unroll
            for (int n2 = 0; n2 < 2; ++n2)
#pragma unroll
                for (int ks = 0; ks < 2; ++ks)
                    acc[m2][2 + n2] = __builtin_amdgcn_mfma_f32_16x16x32_bf16(
                        alo[m2][ks], b1r[n2][ks], acc[m2][2 + n2], 0, 0, 0);
        __builtin_amdgcn_s_setprio(0);
        __builtin_amdgcn_s_barrier();

        // ---------- P2 : read a_hi; stage B(ts) h0+h1; Q11 ----------
        // (legal: all B-row reads of this buffer were consumed by P1-end barrier)
#pragma unroll
        for (int m2 = 0; m2 < 4; ++m2)
#pragma unroll
            for (int ks = 0; ks < 2; ++ks)
                ahi[m2][ks] = *(const short8*)(Ab + aoff + (((4 + m2) * 2 + ks) << 10));
        stageH(B, Bs, col0, ts, 0);
        stageH(B, Bs, col0, ts, 1);
        __builtin_amdgcn_s_barrier();
        asm volatile("s_waitcnt lgkmcnt(0)");
        __builtin_amdgcn_s_setprio(1);
#pragma unroll
        for (int m2 = 0; m2 < 4; ++m2)
#pragma unroll
            for (int n2 = 0; n2 < 2; ++n2)
#pragma unroll
                for (int ks = 0; ks < 2; ++ks)
                    acc[4 + m2][2 + n2] = __builtin_amdgcn_mfma_f32_16x16x32_bf16(
                        ahi[m2][ks], b1r[n2][ks], acc[4 + m2][2 + n2], 0, 0, 0);
        __builtin_amdgcn_s_setprio(0);
        __builtin_amdgcn_s_barrier();

        // ---------- P3 : stage A(ts) h0+h1; Q10; boundary vmcnt(8) ----------
        // (legal: all A-row reads of this buffer consumed by P2-end barrier)
        stageH(A, As, row0, ts, 0);
        stageH(A, As, row0, ts, 1);
        __builtin_amdgcn_s_barrier();
        __builtin_amdgcn_s_setprio(1);
#pragma unroll
        for (int m2 = 0; m2 < 4; ++m2)
#pragma unroll
            for (int n2 = 0; n2 < 2; ++n2)
#pragma unroll
                for (int ks = 0; ks < 2; ++ks)
                    acc[4 + m2][n2] = __builtin_amdgcn_mfma_f32_16x16x32_bf16(
                        ahi[m2][ks], b0r[n2][ks], acc[4 + m2][n2], 0, 0, 0);
        __builtin_amdgcn_s_setprio(0);
        // tile t+1 (staged a full tile ago) must be landed; tile ts' 8 loads fly.
        asm volatile("s_waitcnt vmcnt(8)\ns_barrier" ::: "memory");
    };

#pragma unroll 1
    for (int tt = 0; tt < NT / 2; ++tt) {
        const int t = 2 * tt;
        const int t2 = (t + 2 < NT) ? t + 2 : NT - 1;   // tail: re-stage same bytes
        const int t3 = (t + 3 < NT) ? t + 3 : NT - 1;
        body(t,     A0, B0, A0, B0, t2);
        body(t + 1, A1, B1, A1, B1, t3);
    }
    asm volatile("s_waitcnt vmcnt(0)" ::: "memory");

    // ---- epilogue: D col = lane&15, row = (lane>>4)*4 + r ----
#pragma unroll
    for (int mf = 0; mf < 8; ++mf) {
        const int grow0 = row0 + wr * 128 + mf * 16 + ((l >> 4) << 2);
#pragma unroll
        for (int nf = 0; nf < 4; ++nf) {
            const int gcol = col0 + wc * 64 + nf * 16 + (l & 15);
            float bias_v = 0.f;
            if constexpr (EPI != 1) {
                if (bias) bias_v = bias[gcol];
            }
#pragma unroll
            for (int r = 0; r < 4; ++r) {
                const size_t idx = (size_t)(grow0 + r) * DIM + gcol;
                const float x = acc[mf][nf][r] + bias_v;
                if constexpr (EPI == 0) {
                    ((unsigned short*)Cout)[idx] = f2bf(x);
                } else if constexpr (EPI == 1) {
                    ((float*)Cout)[idx] = x * 0.015625f;   // 1/64
                } else {
                    ((float*)Cout)[idx] = x + res[idx];
                }
            }
        }
    }
}

// ---------------------------------------------------------------------------
__global__ __launch_bounds__(256)
void softmax_kernel(const float* __restrict__ S, unsigned short* __restrict__ P) {
    const int row = blockIdx.x;
    const int t = threadIdx.x;
    const float* src = S + (size_t)row * DIM;

    float v[16];
#pragma unroll
    for (int i = 0; i < 16; ++i) v[i] = src[t + (i << 8)];

    float m = v[0];
#pragma unroll
    for (int i = 1; i < 16; ++i) m = fmaxf(m, v[i]);
#pragma unroll
    for (int off = 32; off > 0; off >>= 1) m = fmaxf(m, __shfl_xor(m, off));

    __shared__ float redm[4], reds[4];
    if ((t & 63) == 0) redm[t >> 6] = m;
    __syncthreads();
    m = fmaxf(fmaxf(redm[0], redm[1]), fmaxf(redm[2], redm[3]));

    float s = 0.f;
#pragma unroll
    for (int i = 0; i < 16; ++i) {
        v[i] = expf(v[i] - m);
        s += v[i];
    }
#pragma unroll
    for (int off = 32; off > 0; off >>= 1) s += __shfl_xor(s, off);
    if ((t & 63) == 0) reds[t >> 6] = s;
    __syncthreads();
    s = (reds[0] + reds[1]) + (reds[2] + reds[3]);

    const float inv = 1.0f / s;
    unsigned short* dst = P + (size_t)row * DIM;
#pragma unroll
    for (int i = 0; i < 16; ++i) dst[t + (i << 8)] = f2bf(v[i] * inv);
}

// ---------------------------------------------------------------------------
extern "C" void kernel_launch(void* const* d_in, const int* in_sizes, int n_in,
                              void* d_out, int out_size, void* d_ws, size_t ws_size,
                              hipStream_t stream) {
    const float* query = (const float*)d_in[0];
    const float* key   = (const float*)d_in[1];
    const float* value = (const float*)d_in[2];
    const float* Wq    = (const float*)d_in[3];
    const float* bq    = (const float*)d_in[4];
    const float* Wk    = (const float*)d_in[5];
    const float* bk    = (const float*)d_in[6];
    const float* Wv    = (const float*)d_in[7];
    const float* bv    = (const float*)d_in[8];
    const float* Wo    = (const float*)d_in[9];
    const float* bo    = (const float*)d_in[10];

    const size_t SZ = (size_t)DIM * DIM;
    unsigned short* qb   = (unsigned short*)d_ws;
    unsigned short* kb   = qb + SZ;
    unsigned short* vb   = kb + SZ;
    unsigned short* xb   = vb + SZ;          // reused cast buffer (inputs)
    unsigned short* wb   = xb + SZ;          // reused cast buffer (weights)
    unsigned short* Pb   = wb + SZ;
    unsigned short* ctxb = Pb + SZ;
    float* scores = (float*)(ctxb + SZ);     // 4*SZ bytes

    const dim3 cg(16384), cb(256);
    const dim3 gg(256), gb(512);

    // q = query @ Wq.T + bq
    cast_kernel<<<cg, cb, 0, stream>>>(query, xb);
    cast_kernel<<<cg, cb, 0, stream>>>(Wq, wb);
    gemm256<0><<<gg, gb, 0, stream>>>(xb, wb, qb, bq, nullptr);
    // k = key @ Wk.T + bk
    cast_kernel<<<cg, cb, 0, stream>>>(key, xb);
    cast_kernel<<<cg, cb, 0, stream>>>(Wk, wb);
    gemm256<0><<<gg, gb, 0, stream>>>(xb, wb, kb, bk, nullptr);
    // v = value @ Wv.T + bv
    cast_kernel<<<cg, cb, 0, stream>>>(value, xb);
    cast_kernel<<<cg, cb, 0, stream>>>(Wv, wb);
    gemm256<0><<<gg, gb, 0, stream>>>(xb, wb, vb, bv, nullptr);
    // scores = q @ k.T / 64   (fp32)
    gemm256<1><<<gg, gb, 0, stream>>>(qb, kb, scores, nullptr, nullptr);
    // P = softmax(scores)  (bf16)
    softmax_kernel<<<4096, 256, 0, stream>>>(scores, Pb);
    // ctx = P @ v.T  (the v-transpose bug makes this NT too)
    gemm256<0><<<gg, gb, 0, stream>>>(Pb, vb, ctxb, nullptr, nullptr);
    // out = ctx @ Wo.T + bo + value   (fp32)
    cast_kernel<<<cg, cb, 0, stream>>>(Wo, wb);
    gemm256<2><<<gg, gb, 0, stream>>>(ctxb, wb, d_out, bo, value);
}

// Round 5
// 814.940 us; speedup vs baseline: 1.5803x; 1.0446x over previous
//
#include <hip/hip_runtime.h>

// ---------------------------------------------------------------------------
// S = D = 4096 single-head attention (with the module's v-transpose bug).
// All six 4096^3 matmuls are NT GEMMs: C[m,n] = sum_k A[m,k]B[n,k].
// Round 5: round-2 schedule with drain/MFMA overlap: per phase only the
// pre-MFMA rendezvous barrier survives (trailing barriers removed), and
// lgkmcnt is left to the compiler's fine-grained per-operand waits.
// Single counted vmcnt(2)+barrier at each K-tile boundary.
// ---------------------------------------------------------------------------

typedef __attribute__((ext_vector_type(4))) float f32x4;
typedef __attribute__((ext_vector_type(8))) short short8;
typedef __attribute__((ext_vector_type(4))) unsigned short us4;

#define DIM 4096
#define NT  64   // K tiles of 64

__device__ __forceinline__ unsigned short f2bf(float f) {
    unsigned int u = __builtin_bit_cast(unsigned int, f);
    u += 0x7fffu + ((u >> 16) & 1u);   // round-to-nearest-even
    return (unsigned short)(u >> 16);
}

__device__ __forceinline__ void gll16(const void* g, void* l) {
    __builtin_amdgcn_global_load_lds(
        (const __attribute__((address_space(1))) unsigned int*)g,
        (__attribute__((address_space(3))) unsigned int*)l,
        16, 0, 0);
}

// ---------------------------------------------------------------------------
__global__ void cast_kernel(const float* __restrict__ in, unsigned short* __restrict__ out) {
    const size_t i = ((size_t)blockIdx.x * 256 + threadIdx.x) * 4;
    float4 x = *(const float4*)(in + i);
    us4 y;
    y.x = f2bf(x.x); y.y = f2bf(x.y); y.z = f2bf(x.z); y.w = f2bf(x.w);
    *(us4*)(out + i) = y;
}

// ---------------------------------------------------------------------------
// 256x256 NT GEMM, BK=64, 8 waves (2x4), 128 KiB LDS dbuf, st_16x32 swizzle
// via pre-swizzled global source.
// Per K-tile t (buffer p = t&1), phases (each with ONE rendezvous barrier):
//   p0: read alo,b0 (12); stage A(t+1)h1; BAR; Q00
//   p1: read b1 (4);      stage B(t+1)h0; BAR; Q01
//   p2: read ahi (8);     stage B(t+1)h1; BAR; Q11
//   p3:                   stage A(t+2)h0; BAR; Q10; [vmcnt(2)+BAR]
// Compiler inserts fine-grained lgkmcnt between ds_read and MFMA, so MFMA
// overlaps the read drain; removed trailing barriers let wave-skew overlap
// one phase's MFMA tail with the next phase's reads.
// EPI: 0 = bf16 out (+opt bias), 1 = f32 out * 1/64, 2 = f32 out + bias + res
// ---------------------------------------------------------------------------
template <int EPI>
__global__ __launch_bounds__(512, 2)
void gemm256(const unsigned short* __restrict__ A, const unsigned short* __restrict__ B,
             void* __restrict__ Cout, const float* __restrict__ bias,
             const float* __restrict__ res) {
    __shared__ alignas(16) char lds[131072];

    const int tid = threadIdx.x;
    const int w = tid >> 6, l = tid & 63;
    const int wr = w >> 2, wc = w & 3;          // 2 x 4 waves, wave tile 128x64

    // bijective XCD swizzle (256 blocks, 8 XCDs)
    const int bid = blockIdx.x;
    const int swz = (bid & 7) * 32 + (bid >> 3);
    const int row0 = (swz >> 4) << 8;
    const int col0 = (swz & 15) << 8;

    // lane constants
    const int laneA  = (l & 15) * 64 + (((l >> 4) << 4) ^ ((l & 8) << 2)); // swizzled frag-read byte
    const int sl_row = l >> 2;                                  // staging row within subtile
    const int sl_col = ((l & 3) << 3) ^ ((l & 32) ? 16 : 0);    // staging col elem (inverse swz)

    f32x4 acc[8][4];
    const f32x4 zero = {0.f, 0.f, 0.f, 0.f};
#pragma unroll
    for (int m = 0; m < 8; ++m)
#pragma unroll
        for (int n = 0; n < 4; ++n) acc[m][n] = zero;

    char* const ldsp = (char*)lds;

    // staging: lane covers subtile row sl_row, inverse-swizzled col sl_col
    auto stage = [&](const unsigned short* __restrict__ M, char* ldsMat, int rowbase,
                     int t, int h) {
        {
            const int rg = h * 8 + (w >> 1), cg = w & 1;
            gll16(M + (size_t)(rowbase + rg * 16 + sl_row) * DIM + t * 64 + cg * 32 + sl_col,
                  ldsMat + ((rg * 2 + cg) << 10));
        }
        {
            const int s = 8 + w;
            const int rg = h * 8 + (s >> 1), cg = s & 1;
            gll16(M + (size_t)(rowbase + rg * 16 + sl_row) * DIM + t * 64 + cg * 32 + sl_col,
                  ldsMat + ((rg * 2 + cg) << 10));
        }
    };

    // ---- prologue: tile0 (4 half-tiles) + A(1)h0; allow A(1)h0 in flight ----
    stage(A, ldsp,          row0, 0, 0);
    stage(A, ldsp,          row0, 0, 1);
    stage(B, ldsp + 32768,  col0, 0, 0);
    stage(B, ldsp + 32768,  col0, 0, 1);
    stage(A, ldsp + 65536,  row0, 1, 0);
    asm volatile("s_waitcnt vmcnt(2)\ns_barrier" ::: "memory");

#pragma unroll 1
    for (int t = 0; t < NT; ++t) {
        const char* Ab = ldsp + (t & 1) * 65536;
        const char* Bb = Ab + 32768;
        const int t1 = (t + 1 < NT) ? t + 1 : NT - 1;   // tail re-stages same bytes
        const int t2 = (t + 2 < NT) ? t + 2 : NT - 1;
        char* A1 = ldsp + (t1 & 1) * 65536;
        char* B1 = A1 + 32768;
        char* A2 = ldsp + (t2 & 1) * 65536;

        const int aoff = wr * 16384 + laneA;
        const int boff = wc * 8192 + laneA;

        short8 a[4][2], b0[2][2], b1[2][2];

        // ================= p0 : read alo,b0; stage A(t+1)h1; Q00 =================
#pragma unroll
        for (int m2 = 0; m2 < 4; ++m2)
#pragma unroll
            for (int ks = 0; ks < 2; ++ks)
                a[m2][ks] = *(const short8*)(Ab + aoff + ((m2 * 2 + ks) << 10));
#pragma unroll
        for (int n2 = 0; n2 < 2; ++n2)
#pragma unroll
            for (int ks = 0; ks < 2; ++ks)
                b0[n2][ks] = *(const short8*)(Bb + boff + ((n2 * 2 + ks) << 10));
        stage(A, A1, row0, t1, 1);
        __builtin_amdgcn_s_barrier();
        __builtin_amdgcn_s_setprio(1);
#pragma unroll
        for (int m2 = 0; m2 < 4; ++m2)
#pragma unroll
            for (int n2 = 0; n2 < 2; ++n2)
#pragma unroll
                for (int ks = 0; ks < 2; ++ks)
                    acc[m2][n2] = __builtin_amdgcn_mfma_f32_16x16x32_bf16(
                        a[m2][ks], b0[n2][ks], acc[m2][n2], 0, 0, 0);
        __builtin_amdgcn_s_setprio(0);

        // ================= p1 : read b1; stage B(t+1)h0; Q01 =================
#pragma unroll
        for (int n2 = 0; n2 < 2; ++n2)
#pragma unroll
            for (int ks = 0; ks < 2; ++ks)
                b1[n2][ks] = *(const short8*)(Bb + boff + (((2 + n2) * 2 + ks) << 10));
        stage(B, B1, col0, t1, 0);
        __builtin_amdgcn_s_barrier();
        __builtin_amdgcn_s_setprio(1);
#pragma unroll
        for (int m2 = 0; m2 < 4; ++m2)
#pragma unroll
            for (int n2 = 0; n2 < 2; ++n2)
#pragma unroll
                for (int ks = 0; ks < 2; ++ks)
                    acc[m2][2 + n2] = __builtin_amdgcn_mfma_f32_16x16x32_bf16(
                        a[m2][ks], b1[n2][ks], acc[m2][2 + n2], 0, 0, 0);
        __builtin_amdgcn_s_setprio(0);

        // ================= p2 : read ahi; stage B(t+1)h1; Q11 =================
#pragma unroll
        for (int m2 = 0; m2 < 4; ++m2)
#pragma unroll
            for (int ks = 0; ks < 2; ++ks)
                a[m2][ks] = *(const short8*)(Ab + aoff + (((4 + m2) * 2 + ks) << 10));
        stage(B, B1, col0, t1, 1);
        __builtin_amdgcn_s_barrier();
        __builtin_amdgcn_s_setprio(1);
#pragma unroll
        for (int m2 = 0; m2 < 4; ++m2)
#pragma unroll
            for (int n2 = 0; n2 < 2; ++n2)
#pragma unroll
                for (int ks = 0; ks < 2; ++ks)
                    acc[4 + m2][2 + n2] = __builtin_amdgcn_mfma_f32_16x16x32_bf16(
                        a[m2][ks], b1[n2][ks], acc[4 + m2][2 + n2], 0, 0, 0);
        __builtin_amdgcn_s_setprio(0);

        // ================= p3 : stage A(t+2)h0; Q10; boundary =================
        stage(A, A2, row0, t2, 0);
        __builtin_amdgcn_s_barrier();
        __builtin_amdgcn_s_setprio(1);
#pragma unroll
        for (int m2 = 0; m2 < 4; ++m2)
#pragma unroll
            for (int n2 = 0; n2 < 2; ++n2)
#pragma unroll
                for (int ks = 0; ks < 2; ++ks)
                    acc[4 + m2][n2] = __builtin_amdgcn_mfma_f32_16x16x32_bf16(
                        a[m2][ks], b0[n2][ks], acc[4 + m2][n2], 0, 0, 0);
        __builtin_amdgcn_s_setprio(0);
        // tile boundary: tile t+1 fully landed (A h1@p0, B h0@p1, B h1@p2,
        // A h0 @ (t-1).p3 all retired); only A(t+2)h0 (2 newest) in flight.
        asm volatile("s_waitcnt vmcnt(2)\ns_barrier" ::: "memory");
    }
    asm volatile("s_waitcnt vmcnt(0)" ::: "memory");

    // ---- epilogue: D col = lane&15, row = (lane>>4)*4 + r ----
#pragma unroll
    for (int mf = 0; mf < 8; ++mf) {
        const int grow0 = row0 + wr * 128 + mf * 16 + ((l >> 4) << 2);
#pragma unroll
        for (int nf = 0; nf < 4; ++nf) {
            const int gcol = col0 + wc * 64 + nf * 16 + (l & 15);
            float bias_v = 0.f;
            if constexpr (EPI != 1) {
                if (bias) bias_v = bias[gcol];
            }
#pragma unroll
            for (int r = 0; r < 4; ++r) {
                const size_t idx = (size_t)(grow0 + r) * DIM + gcol;
                const float x = acc[mf][nf][r] + bias_v;
                if constexpr (EPI == 0) {
                    ((unsigned short*)Cout)[idx] = f2bf(x);
                } else if constexpr (EPI == 1) {
                    ((float*)Cout)[idx] = x * 0.015625f;   // 1/64
                } else {
                    ((float*)Cout)[idx] = x + res[idx];
                }
            }
        }
    }
}

// ---------------------------------------------------------------------------
__global__ __launch_bounds__(256)
void softmax_kernel(const float* __restrict__ S, unsigned short* __restrict__ P) {
    const int row = blockIdx.x;
    const int t = threadIdx.x;
    const float* src = S + (size_t)row * DIM;

    float v[16];
#pragma unroll
    for (int i = 0; i < 16; ++i) v[i] = src[t + (i << 8)];

    float m = v[0];
#pragma unroll
    for (int i = 1; i < 16; ++i) m = fmaxf(m, v[i]);
#pragma unroll
    for (int off = 32; off > 0; off >>= 1) m = fmaxf(m, __shfl_xor(m, off));

    __shared__ float redm[4], reds[4];
    if ((t & 63) == 0) redm[t >> 6] = m;
    __syncthreads();
    m = fmaxf(fmaxf(redm[0], redm[1]), fmaxf(redm[2], redm[3]));

    float s = 0.f;
#pragma unroll
    for (int i = 0; i < 16; ++i) {
        v[i] = expf(v[i] - m);
        s += v[i];
    }
#pragma unroll
    for (int off = 32; off > 0; off >>= 1) s += __shfl_xor(s, off);
    if ((t & 63) == 0) reds[t >> 6] = s;
    __syncthreads();
    s = (reds[0] + reds[1]) + (reds[2] + reds[3]);

    const float inv = 1.0f / s;
    unsigned short* dst = P + (size_t)row * DIM;
#pragma unroll
    for (int i = 0; i < 16; ++i) dst[t + (i << 8)] = f2bf(v[i] * inv);
}

// ---------------------------------------------------------------------------
extern "C" void kernel_launch(void* const* d_in, const int* in_sizes, int n_in,
                              void* d_out, int out_size, void* d_ws, size_t ws_size,
                              hipStream_t stream) {
    const float* query = (const float*)d_in[0];
    const float* key   = (const float*)d_in[1];
    const float* value = (const float*)d_in[2];
    const float* Wq    = (const float*)d_in[3];
    const float* bq    = (const float*)d_in[4];
    const float* Wk    = (const float*)d_in[5];
    const float* bk    = (const float*)d_in[6];
    const float* Wv    = (const float*)d_in[7];
    const float* bv    = (const float*)d_in[8];
    const float* Wo    = (const float*)d_in[9];
    const float* bo    = (const float*)d_in[10];

    const size_t SZ = (size_t)DIM * DIM;
    unsigned short* qb   = (unsigned short*)d_ws;
    unsigned short* kb   = qb + SZ;
    unsigned short* vb   = kb + SZ;
    unsigned short* xb   = vb + SZ;          // reused cast buffer (inputs)
    unsigned short* wb   = xb + SZ;          // reused cast buffer (weights)
    unsigned short* Pb   = wb + SZ;
    unsigned short* ctxb = Pb + SZ;
    float* scores = (float*)(ctxb + SZ);     // 4*SZ bytes

    const dim3 cg(16384), cb(256);
    const dim3 gg(256), gb(512);

    // q = query @ Wq.T + bq
    cast_kernel<<<cg, cb, 0, stream>>>(query, xb);
    cast_kernel<<<cg, cb, 0, stream>>>(Wq, wb);
    gemm256<0><<<gg, gb, 0, stream>>>(xb, wb, qb, bq, nullptr);
    // k = key @ Wk.T + bk
    cast_kernel<<<cg, cb, 0, stream>>>(key, xb);
    cast_kernel<<<cg, cb, 0, stream>>>(Wk, wb);
    gemm256<0><<<gg, gb, 0, stream>>>(xb, wb, kb, bk, nullptr);
    // v = value @ Wv.T + bv
    cast_kernel<<<cg, cb, 0, stream>>>(value, xb);
    cast_kernel<<<cg, cb, 0, stream>>>(Wv, wb);
    gemm256<0><<<gg, gb, 0, stream>>>(xb, wb, vb, bv, nullptr);
    // scores = q @ k.T / 64   (fp32)
    gemm256<1><<<gg, gb, 0, stream>>>(qb, kb, scores, nullptr, nullptr);
    // P = softmax(scores)  (bf16)
    softmax_kernel<<<4096, 256, 0, stream>>>(scores, Pb);
    // ctx = P @ v.T  (the v-transpose bug makes this NT too)
    gemm256<0><<<gg, gb, 0, stream>>>(Pb, vb, ctxb, nullptr, nullptr);
    // out = ctx @ Wo.T + bo + value   (fp32)
    cast_kernel<<<cg, cb, 0, stream>>>(Wo, wb);
    gemm256<2><<<gg, gb, 0, stream>>>(ctxb, wb, d_out, bo, value);
}

// Round 6
// 796.128 us; speedup vs baseline: 1.6176x; 1.0236x over previous
//
#include <hip/hip_runtime.h>

// ---------------------------------------------------------------------------
// S = D = 4096 single-head attention (with the module's v-transpose bug).
// All six 4096^3 matmuls are NT GEMMs: C[m,n] = sum_k A[m,k]B[n,k].
// Round 6: r5 staging/vmcnt + intra-tile ds_read software pipelining:
//   p0: read b0,alo (exposed); stage A(t+1)h1; Q00
//   p1: read b1,ahi (hidden);  stage B(t+1)h0; Q01
//   R1 barrier (all tile-t reads issued)
//   p2:                        stage B(t+1)h1; Q11   (all-register)
//   p3:                        stage A(t+2)h0; Q10   (all-register)
//   boundary: vmcnt(2)+barrier
// ---------------------------------------------------------------------------

typedef __attribute__((ext_vector_type(4))) float f32x4;
typedef __attribute__((ext_vector_type(8))) short short8;
typedef __attribute__((ext_vector_type(4))) unsigned short us4;

#define DIM 4096
#define NT  64   // K tiles of 64

__device__ __forceinline__ unsigned short f2bf(float f) {
    unsigned int u = __builtin_bit_cast(unsigned int, f);
    u += 0x7fffu + ((u >> 16) & 1u);   // round-to-nearest-even
    return (unsigned short)(u >> 16);
}

__device__ __forceinline__ void gll16(const void* g, void* l) {
    __builtin_amdgcn_global_load_lds(
        (const __attribute__((address_space(1))) unsigned int*)g,
        (__attribute__((address_space(3))) unsigned int*)l,
        16, 0, 0);
}

// ---------------------------------------------------------------------------
__global__ void cast_kernel(const float* __restrict__ in, unsigned short* __restrict__ out) {
    const size_t i = ((size_t)blockIdx.x * 256 + threadIdx.x) * 4;
    float4 x = *(const float4*)(in + i);
    us4 y;
    y.x = f2bf(x.x); y.y = f2bf(x.y); y.z = f2bf(x.z); y.w = f2bf(x.w);
    *(us4*)(out + i) = y;
}

// ---------------------------------------------------------------------------
// 256x256 NT GEMM, BK=64, 8 waves (2x4), 128 KiB LDS dbuf, st_16x32 swizzle
// via pre-swizzled global source. See header for the per-tile schedule.
// WAR safety: A(t+1)/B(t+1) stage targets were last read in tile t-1
// (protected by the boundary barrier); A(t+2)'s target is read as alo/ahi(t)
// at p0/p1 of this tile (protected by R1).
// EPI: 0 = bf16 out (+opt bias), 1 = f32 out * 1/64, 2 = f32 out + bias + res
// ---------------------------------------------------------------------------
template <int EPI>
__global__ __launch_bounds__(512, 2)
void gemm256(const unsigned short* __restrict__ A, const unsigned short* __restrict__ B,
             void* __restrict__ Cout, const float* __restrict__ bias,
             const float* __restrict__ res) {
    __shared__ alignas(16) char lds[131072];

    const int tid = threadIdx.x;
    const int w = tid >> 6, l = tid & 63;
    const int wr = w >> 2, wc = w & 3;          // 2 x 4 waves, wave tile 128x64

    // bijective XCD swizzle (256 blocks, 8 XCDs)
    const int bid = blockIdx.x;
    const int swz = (bid & 7) * 32 + (bid >> 3);
    const int row0 = (swz >> 4) << 8;
    const int col0 = (swz & 15) << 8;

    // lane constants
    const int laneA  = (l & 15) * 64 + (((l >> 4) << 4) ^ ((l & 8) << 2)); // swizzled frag-read byte
    const int sl_row = l >> 2;                                  // staging row within subtile
    const int sl_col = ((l & 3) << 3) ^ ((l & 32) ? 16 : 0);    // staging col elem (inverse swz)

    f32x4 acc[8][4];
    const f32x4 zero = {0.f, 0.f, 0.f, 0.f};
#pragma unroll
    for (int m = 0; m < 8; ++m)
#pragma unroll
        for (int n = 0; n < 4; ++n) acc[m][n] = zero;

    char* const ldsp = (char*)lds;

    // staging: lane covers subtile row sl_row, inverse-swizzled col sl_col
    auto stage = [&](const unsigned short* __restrict__ M, char* ldsMat, int rowbase,
                     int t, int h) {
        {
            const int rg = h * 8 + (w >> 1), cg = w & 1;
            gll16(M + (size_t)(rowbase + rg * 16 + sl_row) * DIM + t * 64 + cg * 32 + sl_col,
                  ldsMat + ((rg * 2 + cg) << 10));
        }
        {
            const int s = 8 + w;
            const int rg = h * 8 + (s >> 1), cg = s & 1;
            gll16(M + (size_t)(rowbase + rg * 16 + sl_row) * DIM + t * 64 + cg * 32 + sl_col,
                  ldsMat + ((rg * 2 + cg) << 10));
        }
    };

    // ---- prologue: tile0 (4 half-tiles) + A(1)h0; allow A(1)h0 in flight ----
    stage(A, ldsp,          row0, 0, 0);
    stage(A, ldsp,          row0, 0, 1);
    stage(B, ldsp + 32768,  col0, 0, 0);
    stage(B, ldsp + 32768,  col0, 0, 1);
    stage(A, ldsp + 65536,  row0, 1, 0);
    asm volatile("s_waitcnt vmcnt(2)\ns_barrier" ::: "memory");

#pragma unroll 1
    for (int t = 0; t < NT; ++t) {
        const char* Ab = ldsp + (t & 1) * 65536;
        const char* Bb = Ab + 32768;
        const int t1 = (t + 1 < NT) ? t + 1 : NT - 1;   // tail re-stages same bytes
        const int t2 = (t + 2 < NT) ? t + 2 : NT - 1;
        char* A1 = ldsp + (t1 & 1) * 65536;
        char* B1 = A1 + 32768;
        char* A2 = ldsp + (t2 & 1) * 65536;

        const int aoff = wr * 16384 + laneA;
        const int boff = wc * 8192 + laneA;

        short8 alo[4][2], ahi[4][2], b0[2][2], b1[2][2];

        // ====== p0 : read b0, alo (this phase); stage A(t+1)h1; Q00 ======
#pragma unroll
        for (int n2 = 0; n2 < 2; ++n2)
#pragma unroll
            for (int ks = 0; ks < 2; ++ks)
                b0[n2][ks] = *(const short8*)(Bb + boff + ((n2 * 2 + ks) << 10));
#pragma unroll
        for (int m2 = 0; m2 < 4; ++m2)
#pragma unroll
            for (int ks = 0; ks < 2; ++ks)
                alo[m2][ks] = *(const short8*)(Ab + aoff + ((m2 * 2 + ks) << 10));
        stage(A, A1, row0, t1, 1);
        __builtin_amdgcn_s_setprio(1);
#pragma unroll
        for (int m2 = 0; m2 < 4; ++m2)
#pragma unroll
            for (int n2 = 0; n2 < 2; ++n2)
#pragma unroll
                for (int ks = 0; ks < 2; ++ks)
                    acc[m2][n2] = __builtin_amdgcn_mfma_f32_16x16x32_bf16(
                        alo[m2][ks], b0[n2][ks], acc[m2][n2], 0, 0, 0);
        __builtin_amdgcn_s_setprio(0);

        // ====== p1 : read b1, ahi (next phases, hidden); stage B(t+1)h0; Q01 ======
#pragma unroll
        for (int n2 = 0; n2 < 2; ++n2)
#pragma unroll
            for (int ks = 0; ks < 2; ++ks)
                b1[n2][ks] = *(const short8*)(Bb + boff + (((2 + n2) * 2 + ks) << 10));
#pragma unroll
        for (int m2 = 0; m2 < 4; ++m2)
#pragma unroll
            for (int ks = 0; ks < 2; ++ks)
                ahi[m2][ks] = *(const short8*)(Ab + aoff + (((4 + m2) * 2 + ks) << 10));
        stage(B, B1, col0, t1, 0);
        __builtin_amdgcn_s_setprio(1);
#pragma unroll
        for (int m2 = 0; m2 < 4; ++m2)
#pragma unroll
            for (int n2 = 0; n2 < 2; ++n2)
#pragma unroll
                for (int ks = 0; ks < 2; ++ks)
                    acc[m2][2 + n2] = __builtin_amdgcn_mfma_f32_16x16x32_bf16(
                        alo[m2][ks], b1[n2][ks], acc[m2][2 + n2], 0, 0, 0);
        __builtin_amdgcn_s_setprio(0);

        // R1: all tile-t LDS reads issued by every wave; after this it is
        // safe for p3 to stage into the alo/ahi(t) region (A(t+2)h0).
        asm volatile("s_barrier" ::: "memory");

        // ====== p2 : stage B(t+1)h1; Q11 (all-register) ======
        stage(B, B1, col0, t1, 1);
        __builtin_amdgcn_s_setprio(1);
#pragma unroll
        for (int m2 = 0; m2 < 4; ++m2)
#pragma unroll
            for (int n2 = 0; n2 < 2; ++n2)
#pragma unroll
                for (int ks = 0; ks < 2; ++ks)
                    acc[4 + m2][2 + n2] = __builtin_amdgcn_mfma_f32_16x16x32_bf16(
                        ahi[m2][ks], b1[n2][ks], acc[4 + m2][2 + n2], 0, 0, 0);
        __builtin_amdgcn_s_setprio(0);

        // ====== p3 : stage A(t+2)h0; Q10 (all-register); boundary ======
        stage(A, A2, row0, t2, 0);
        __builtin_amdgcn_s_setprio(1);
#pragma unroll
        for (int m2 = 0; m2 < 4; ++m2)
#pragma unroll
            for (int n2 = 0; n2 < 2; ++n2)
#pragma unroll
                for (int ks = 0; ks < 2; ++ks)
                    acc[4 + m2][n2] = __builtin_amdgcn_mfma_f32_16x16x32_bf16(
                        ahi[m2][ks], b0[n2][ks], acc[4 + m2][n2], 0, 0, 0);
        __builtin_amdgcn_s_setprio(0);
        // tile boundary: tile t+1 fully landed (A h1@p0, B h0@p1, B h1@p2,
        // A h0 @ (t-1).p3 all retired); only A(t+2)h0 (2 newest) in flight.
        asm volatile("s_waitcnt vmcnt(2)\ns_barrier" ::: "memory");
    }
    asm volatile("s_waitcnt vmcnt(0)" ::: "memory");

    // ---- epilogue: D col = lane&15, row = (lane>>4)*4 + r ----
#pragma unroll
    for (int mf = 0; mf < 8; ++mf) {
        const int grow0 = row0 + wr * 128 + mf * 16 + ((l >> 4) << 2);
#pragma unroll
        for (int nf = 0; nf < 4; ++nf) {
            const int gcol = col0 + wc * 64 + nf * 16 + (l & 15);
            float bias_v = 0.f;
            if constexpr (EPI != 1) {
                if (bias) bias_v = bias[gcol];
            }
#pragma unroll
            for (int r = 0; r < 4; ++r) {
                const size_t idx = (size_t)(grow0 + r) * DIM + gcol;
                const float x = acc[mf][nf][r] + bias_v;
                if constexpr (EPI == 0) {
                    ((unsigned short*)Cout)[idx] = f2bf(x);
                } else if constexpr (EPI == 1) {
                    ((float*)Cout)[idx] = x * 0.015625f;   // 1/64
                } else {
                    ((float*)Cout)[idx] = x + res[idx];
                }
            }
        }
    }
}

// ---------------------------------------------------------------------------
__global__ __launch_bounds__(256)
void softmax_kernel(const float* __restrict__ S, unsigned short* __restrict__ P) {
    const int row = blockIdx.x;
    const int t = threadIdx.x;
    const float* src = S + (size_t)row * DIM;

    float v[16];
#pragma unroll
    for (int i = 0; i < 16; ++i) v[i] = src[t + (i << 8)];

    float m = v[0];
#pragma unroll
    for (int i = 1; i < 16; ++i) m = fmaxf(m, v[i]);
#pragma unroll
    for (int off = 32; off > 0; off >>= 1) m = fmaxf(m, __shfl_xor(m, off));

    __shared__ float redm[4], reds[4];
    if ((t & 63) == 0) redm[t >> 6] = m;
    __syncthreads();
    m = fmaxf(fmaxf(redm[0], redm[1]), fmaxf(redm[2], redm[3]));

    float s = 0.f;
#pragma unroll
    for (int i = 0; i < 16; ++i) {
        v[i] = expf(v[i] - m);
        s += v[i];
    }
#pragma unroll
    for (int off = 32; off > 0; off >>= 1) s += __shfl_xor(s, off);
    if ((t & 63) == 0) reds[t >> 6] = s;
    __syncthreads();
    s = (reds[0] + reds[1]) + (reds[2] + reds[3]);

    const float inv = 1.0f / s;
    unsigned short* dst = P + (size_t)row * DIM;
#pragma unroll
    for (int i = 0; i < 16; ++i) dst[t + (i << 8)] = f2bf(v[i] * inv);
}

// ---------------------------------------------------------------------------
extern "C" void kernel_launch(void* const* d_in, const int* in_sizes, int n_in,
                              void* d_out, int out_size, void* d_ws, size_t ws_size,
                              hipStream_t stream) {
    const float* query = (const float*)d_in[0];
    const float* key   = (const float*)d_in[1];
    const float* value = (const float*)d_in[2];
    const float* Wq    = (const float*)d_in[3];
    const float* bq    = (const float*)d_in[4];
    const float* Wk    = (const float*)d_in[5];
    const float* bk    = (const float*)d_in[6];
    const float* Wv    = (const float*)d_in[7];
    const float* bv    = (const float*)d_in[8];
    const float* Wo    = (const float*)d_in[9];
    const float* bo    = (const float*)d_in[10];

    const size_t SZ = (size_t)DIM * DIM;
    unsigned short* qb   = (unsigned short*)d_ws;
    unsigned short* kb   = qb + SZ;
    unsigned short* vb   = kb + SZ;
    unsigned short* xb   = vb + SZ;          // reused cast buffer (inputs)
    unsigned short* wb   = xb + SZ;          // reused cast buffer (weights)
    unsigned short* Pb   = wb + SZ;
    unsigned short* ctxb = Pb + SZ;
    float* scores = (float*)(ctxb + SZ);     // 4*SZ bytes

    const dim3 cg(16384), cb(256);
    const dim3 gg(256), gb(512);

    // q = query @ Wq.T + bq
    cast_kernel<<<cg, cb, 0, stream>>>(query, xb);
    cast_kernel<<<cg, cb, 0, stream>>>(Wq, wb);
    gemm256<0><<<gg, gb, 0, stream>>>(xb, wb, qb, bq, nullptr);
    // k = key @ Wk.T + bk
    cast_kernel<<<cg, cb, 0, stream>>>(key, xb);
    cast_kernel<<<cg, cb, 0, stream>>>(Wk, wb);
    gemm256<0><<<gg, gb, 0, stream>>>(xb, wb, kb, bk, nullptr);
    // v = value @ Wv.T + bv
    cast_kernel<<<cg, cb, 0, stream>>>(value, xb);
    cast_kernel<<<cg, cb, 0, stream>>>(Wv, wb);
    gemm256<0><<<gg, gb, 0, stream>>>(xb, wb, vb, bv, nullptr);
    // scores = q @ k.T / 64   (fp32)
    gemm256<1><<<gg, gb, 0, stream>>>(qb, kb, scores, nullptr, nullptr);
    // P = softmax(scores)  (bf16)
    softmax_kernel<<<4096, 256, 0, stream>>>(scores, Pb);
    // ctx = P @ v.T  (the v-transpose bug makes this NT too)
    gemm256<0><<<gg, gb, 0, stream>>>(Pb, vb, ctxb, nullptr, nullptr);
    // out = ctx @ Wo.T + bo + value   (fp32)
    cast_kernel<<<cg, cb, 0, stream>>>(Wo, wb);
    gemm256<2><<<gg, gb, 0, stream>>>(ctxb, wb, d_out, bo, value);
}